// Round 5
// baseline (656.800 us; speedup 1.0000x reference)
//
#include <hip/hip_runtime.h>

// 18-wire, 3-layer batched statevector sim — TWO-PASS wavefront schedule.
//
// Circuit per layer l: SQ_l on all 18 bits + CNOT chain C_l(17,16)..(1,0).
// Reorder (exact, by commutation): layer l = descending stream of
//   O_l(p) = [SQ_l(p), C_l(p+1,p)],  with dependency O_{l+1}(p) after O_l(p-1).
// Pass 1 (window bits 17..7):  O_0(17..7), O_1(17..8), O_2(17..9)
// Pass 2 (window bits 10..0):  O_0(6..0),  O_1(7..0),  O_2(8..0) + measure.
// Within a mini (one layer's ops in the window): all SQs first, then its CNOT
// chain — which is a classical XOR-permutation (suffix-xor) folded into the
// NEXT LDS-transpose's write addressing (zero data movement).
//
// Layouts:  input fp32 planes (natural), intermediate = packed bf16 (re|im<<16)
// written IN-PLACE into d_in[0] at shuffled address sigma = hi7<<11|m4<<7|f7
// (hi7=n17..11, m4=n10..7, f7=n6..0): per-wave read-set == write-set (race-free),
// and pass-2's window (n10..0) becomes contiguous low-11 bits (perfect loads).
// Zero __syncthreads anywhere. LDS transposes are wave-local:
// addr = row*36 + (pos ^ ((row>>3&7)<<2))  (16B-aligned xor swizzle, <=2-way banks).

#define NW 36

static __device__ __forceinline__ float rfl(float x){
  return __int_as_float(__builtin_amdgcn_readfirstlane(__float_as_int(x)));
}
static __device__ __forceinline__ unsigned sfx11(unsigned x){  // suffix-xor, 11 bits
  x ^= x>>1; x ^= x>>2; x ^= x>>4; x ^= x>>8; return x & 0x7FFu;
}
static __device__ __forceinline__ int lofs(int row, int pos){
  return row*NW + (pos ^ (((row>>3)&7)<<2));
}
static __device__ __forceinline__ unsigned packbf(float a, float b){  // RNE
  unsigned ua = __float_as_uint(a); ua += 0x7FFFu + ((ua>>16)&1u);
  unsigned ub = __float_as_uint(b); ub += 0x7FFFu + ((ub>>16)&1u);
  return (ua>>16) | (ub & 0xFFFF0000u);
}
static __device__ __forceinline__ void unpack2(unsigned u, float& a, float& b){
  a = __uint_as_float(u<<16); b = __uint_as_float(u & 0xFFFF0000u);
}
static __device__ __forceinline__ void sq_pair(float& a0r,float& a0i,float& a1r,float& a1i,
                                               float c,float s,float pc,float ps){
  const float t0r = fmaf(c,a0r,-(s*a1r));
  const float t0i = fmaf(c,a0i,-(s*a1i));
  const float t1r = fmaf(s,a0r, c*a1r);
  const float t1i = fmaf(s,a0i, c*a1i);
  a0r=t0r; a0i=t0i;
  a1r = fmaf(pc,t1r,-(ps*t1i));
  a1i = fmaf(pc,t1i, (ps*t1r));
}
template<int J>
static __device__ __forceinline__ void sqg(float* ar,float* ai,float c,float s,float pc,float ps){
#pragma unroll
  for(int r=0;r<32;++r) if(((r>>J)&1)==0){
    const int r1 = r + (1<<J);
    sq_pair(ar[r],ai[r],ar[r1],ai[r1],c,s,pc,ps);
  }
}
template<int J>
static __device__ __forceinline__ void gate(float* ar,float* ai,const float* pl,int wire){
  float sv,cv;
  __sincosf(0.5f*pl[wire],&sv,&cv); const float s=rfl(sv), c=rfl(cv);
  __sincosf(pl[18+wire],&sv,&cv);   const float ps=rfl(sv), pc=rfl(cv);
  sqg<J>(ar,ai,c,s,pc,ps);
}
// SQ on lane-bit 5 (partner = lane ^ 32)
static __device__ __forceinline__ void gate_l5(float* ar,float* ai,const float* pl,int wire,int l){
  float sv,cv;
  __sincosf(0.5f*pl[wire],&sv,&cv); const float s=rfl(sv), c=rfl(cv);
  __sincosf(pl[18+wire],&sv,&cv);   const float ps=rfl(sv), pc=rfl(cv);
  const int side = (l>>5)&1;
  const float bco = side ? s : -s;
  const float qc  = side ? pc : 1.f;
  const float qs  = side ? ps : 0.f;
#pragma unroll
  for(int r=0;r<32;++r){
    const float pr = __shfl_xor(ar[r],32);
    const float pi = __shfl_xor(ai[r],32);
    const float tr = fmaf(c,ar[r],bco*pr);
    const float ti = fmaf(c,ai[r],bco*pi);
    ar[r] = fmaf(qc,tr,-(qs*ti));
    ai[r] = fmaf(qc,ti, (qs*tr));
  }
}

#define XPOSE(AEXPR)                                                          \
  {                                                                           \
    int a[32];                                                                \
    _Pragma("unroll") for(int r=0;r<32;++r){ AEXPR; }                         \
    _Pragma("unroll") for(int r=0;r<32;++r) Lb[a[r]] = ar[r];                 \
    _Pragma("unroll") for(int q=0;q<8;++q){                                   \
      const float4 v=*(const float4*)&Lb[lofs(l,q<<2)];                       \
      ar[4*q]=v.x; ar[4*q+1]=v.y; ar[4*q+2]=v.z; ar[4*q+3]=v.w; }             \
    _Pragma("unroll") for(int r=0;r<32;++r) Lb[a[r]] = ai[r];                 \
    _Pragma("unroll") for(int q=0;q<8;++q){                                   \
      const float4 v=*(const float4*)&Lb[lofs(l,q<<2)];                       \
      ai[4*q]=v.x; ai[4*q+1]=v.y; ai[4*q+2]=v.z; ai[4*q+3]=v.w; }             \
  }

// ================= PASS 1: window w = n17..n7 (w_j = n_{7+j}, wire 10-j) =================
// Block = 256 thr = 4 waves sharing an f-quad (L1 line reuse on strided fp32 loads).
// XCD swizzle: blk&7 selects the f-16-group so sector-sharing blocks hit one XCD L2.
// re / up alias d_in[0] by design (in-place, per-wave footprint closed) — no restrict.
__global__ __launch_bounds__(256,4) void pass1_k(const float* re, const float* __restrict__ im,
                                                 unsigned* up, const float* __restrict__ params)
{
  __shared__ __align__(16) float lds[4*2304];
  const int t = threadIdx.x, l = t&63, j = t>>6;
  float* Lb = lds + j*2304;
  const int blk = blockIdx.x;
  const int Xg = blk&7, q2 = blk>>3;
  const int b = q2>>2, fq = (Xg<<2)|(q2&3);
  const int f = (fq<<2)|j;
  const unsigned base = ((unsigned)b<<18) | (unsigned)f;
  const float* pl0 = params;
  const float* pl1 = params+36;
  const float* pl2 = params+72;

  // P0 roles: regs = w10..w6, lanes = w5..w0.  Load (strided; L1 shares f-quad lines)
  float ar[32], ai[32];
#pragma unroll
  for(int r=0;r<32;++r){
    const unsigned n = base + (unsigned)(r<<13) + (unsigned)(l<<7);
    ar[r]=re[n]; ai[r]=im[n];
  }

  // ---- mini 0 (layer 0, SQ on w10..w0) ----
  gate<4>(ar,ai,pl0,0); gate<3>(ar,ai,pl0,1); gate<2>(ar,ai,pl0,2);
  gate<1>(ar,ai,pl0,3); gate<0>(ar,ai,pl0,4);
  // T1 (role swap only): out regs = w4..w0, out lanes = [w5 | w10..w6]
  XPOSE( a[r]=lofs((l&32)|r, l&31) )
  gate<4>(ar,ai,pl0,6); gate<3>(ar,ai,pl0,7); gate<2>(ar,ai,pl0,8);
  gate<1>(ar,ai,pl0,9); gate<0>(ar,ai,pl0,10);
  gate_l5(ar,ai,pl0,5,l);
  // chain0 = C_0(17,16)..(8,7): w' = sfx11(w).  Fold into T2.
  // T2: out regs = w'10..w'6, out lanes = w'5..w'0
  XPOSE( const unsigned w=((unsigned)(l&31)<<6)|((unsigned)(l>>5)<<5)|(unsigned)r; \
         const unsigned wp=sfx11(w); a[r]=lofs((int)(wp&63u),(int)(wp>>6)) )

  // ---- mini 1 (layer 1, SQ on w10..w1) ----
  gate<4>(ar,ai,pl1,0); gate<3>(ar,ai,pl1,1); gate<2>(ar,ai,pl1,2);
  gate<1>(ar,ai,pl1,3); gate<0>(ar,ai,pl1,4);
  // T3: out regs = w5..w1, out lanes = [w0 | w10..w6]
  XPOSE( a[r]=lofs(((l&1)<<5)|r, l>>1) )
  gate<4>(ar,ai,pl1,5); gate<3>(ar,ai,pl1,6); gate<2>(ar,ai,pl1,7);
  gate<1>(ar,ai,pl1,8); gate<0>(ar,ai,pl1,9);
  // chain1 = C_1(17,16)..(9,8): w'' = (sfx11(w') & ~1) | (w' & 1).  Fold into T4.
  XPOSE( const unsigned w=((unsigned)(l&31)<<6)|((unsigned)r<<1)|(unsigned)(l>>5); \
         const unsigned wp=(sfx11(w)&~1u)|(w&1u); a[r]=lofs((int)(wp&63u),(int)(wp>>6)) )

  // ---- mini 2 (layer 2, SQ on w10..w2) ----
  gate<4>(ar,ai,pl2,0); gate<3>(ar,ai,pl2,1); gate<2>(ar,ai,pl2,2);
  gate<1>(ar,ai,pl2,3); gate<0>(ar,ai,pl2,4);
  // T5: out regs = w5..w1, out lanes = [w0 | w10..w6]
  XPOSE( a[r]=lofs(((l&1)<<5)|r, l>>1) )
  gate<4>(ar,ai,pl2,5); gate<3>(ar,ai,pl2,6); gate<2>(ar,ai,pl2,7);
  gate<1>(ar,ai,pl2,8);
  // chain2 = C_2(17,16)..(10,9): w''' = (sfx11(w'') & ~3) | (w'' & 3). Fold into store.
  // Store packed bf16 at sigma = hi7<<11 | m4<<7 | f  (hi7=w'''10..4, m4=w'''3..0)
#pragma unroll
  for(int r=0;r<32;++r){
    const unsigned w2 = ((unsigned)(l&31)<<6)|((unsigned)r<<1)|(unsigned)(l>>5);
    const unsigned w3 = (sfx11(w2)&~3u)|(w2&3u);
    const unsigned sg = ((w3>>4)<<11) | ((w3&15u)<<7) | (unsigned)f;
    up[((unsigned)b<<18) | sg] = packbf(ar[r], ai[r]);
  }
}

// ================= PASS 2: window v = n10..n0 (v_j = n_j, wire 17-j) + measure =================
// sigma-layout: v = low 11 bits of address -> contiguous 8KB per wave.
// Block = 2 waves = adjacent hi7 pair (shares 128B lines).
__global__ __launch_bounds__(128,4) void pass2_k(const unsigned* __restrict__ up,
                                                 const float* __restrict__ params,
                                                 const float* __restrict__ hw,
                                                 const float* __restrict__ hb,
                                                 float* __restrict__ out)
{
  __shared__ __align__(16) float lds[2*2304];
  const int t = threadIdx.x, l = t&63, wib = t>>6;
  float* Lb = lds + wib*2304;
  const int b = blockIdx.x>>6;
  const int hi7 = ((blockIdx.x&63)<<1)|wib;
  const unsigned base = ((unsigned)b<<18)|((unsigned)hi7<<11);
  const float* pl0 = params;
  const float* pl1 = params+36;
  const float* pl2 = params+72;

  // P0 roles: regs = [v10 v9 v8 | v1 v0] (r=g<<2|q), lanes = [v7 | v6..v2]
  uint4 U[8];
#pragma unroll
  for(int g=0; g<8; ++g)
    U[g] = *(const uint4*)&up[base + (unsigned)(g<<8) + (unsigned)(l<<2)];

  float c16,s16,pc16,ps16, c17,s17,pc17,ps17;
  { float sv,cv;
    __sincosf(0.5f*pl0[16],&sv,&cv); s16=rfl(sv); c16=rfl(cv);
    __sincosf(pl0[18+16],&sv,&cv);   ps16=rfl(sv); pc16=rfl(cv);
    __sincosf(0.5f*pl0[17],&sv,&cv); s17=rfl(sv); c17=rfl(cv);
    __sincosf(pl0[18+17],&sv,&cv);   ps17=rfl(sv); pc17=rfl(cv); }

  float ar[32], ai[32];
#pragma unroll
  for(int g=0; g<8; ++g){                      // unpack + L0 quad gates as loads land
    unpack2(U[g].x, ar[4*g+0], ai[4*g+0]);
    unpack2(U[g].y, ar[4*g+1], ai[4*g+1]);
    unpack2(U[g].z, ar[4*g+2], ai[4*g+2]);
    unpack2(U[g].w, ar[4*g+3], ai[4*g+3]);
    sq_pair(ar[4*g+0],ai[4*g+0],ar[4*g+2],ai[4*g+2], c16,s16,pc16,ps16); // v1, wire16
    sq_pair(ar[4*g+1],ai[4*g+1],ar[4*g+3],ai[4*g+3], c16,s16,pc16,ps16);
    sq_pair(ar[4*g+0],ai[4*g+0],ar[4*g+1],ai[4*g+1], c17,s17,pc17,ps17); // v0, wire17
    sq_pair(ar[4*g+2],ai[4*g+2],ar[4*g+3],ai[4*g+3], c17,s17,pc17,ps17);
  }

  // T1 (role swap): out regs = v6..v2, out lanes = [v10 v9 v8 v7 v1 v0]
  XPOSE( a[r]=lofs(((r&0x1C)<<1)|((l>>5)<<2)|(r&3), l&31) )
  gate<4>(ar,ai,pl0,11); gate<3>(ar,ai,pl0,12); gate<2>(ar,ai,pl0,13);
  gate<1>(ar,ai,pl0,14); gate<0>(ar,ai,pl0,15);
  // chain0 = C_0(7,6)..(1,0): v'_p = s_p^s_8 (p<=6). Fold into T2.
  // T2: out regs = v7..v3, out lanes = [v10 v9 v8 v2 v1 v0]
  XPOSE( const unsigned v=((unsigned)(l>>5)<<10)|((unsigned)((l>>4)&1)<<9)|((unsigned)((l>>3)&1)<<8) \
              |((unsigned)((l>>2)&1)<<7)|((unsigned)r<<2)|((unsigned)((l>>1)&1)<<1)|(unsigned)(l&1);  \
         const unsigned s=sfx11(v);                                                                    \
         const unsigned vp=(v&0x780u)|((((s>>8)&1u)? (s^0x7Fu):s)&0x7Fu);                              \
         a[r]=lofs((int)((((vp>>10)&1u)<<5)|(((vp>>9)&1u)<<4)|(((vp>>8)&1u)<<3)|(vp&7u)),              \
                   (int)((vp>>3)&31u)) )
  gate<4>(ar,ai,pl1,10); gate<3>(ar,ai,pl1,11); gate<2>(ar,ai,pl1,12);
  gate<1>(ar,ai,pl1,13); gate<0>(ar,ai,pl1,14);
  // T3 (role swap): out regs = [v2 v1 v0 v10 v9], out lanes = [v8 v7 v6 v5 v4 v3]
  XPOSE( const unsigned v=((unsigned)(l>>5)<<10)|((unsigned)((l>>4)&1)<<9)|((unsigned)((l>>3)&1)<<8) \
              |((unsigned)r<<3)|(unsigned)(l&7);                                                       \
         a[r]=lofs((int)((v>>3)&63u), (int)(((v&7u)<<2)|(((v>>10)&1u)<<1)|((v>>9)&1u))) )
  gate<4>(ar,ai,pl1,15); gate<3>(ar,ai,pl1,16); gate<2>(ar,ai,pl1,17);
  // chain1 = C_1(8,7)..(1,0): v''_p = s_p^s_9 (p<=7). Fold into T4.
  // T4: out regs = v8..v4, out lanes = [v10 v9 v3 v2 v1 v0]
  XPOSE( const unsigned v=((unsigned)((r>>1)&1)<<10)|((unsigned)(r&1)<<9)|((unsigned)(l&63)<<3)       \
              |((unsigned)((r>>4)&1)<<2)|((unsigned)((r>>3)&1)<<1)|(unsigned)((r>>2)&1);               \
         const unsigned s=sfx11(v);                                                                    \
         const unsigned vp=(v&0x700u)|((((s>>9)&1u)? (s^0xFFu):s)&0xFFu);                              \
         a[r]=lofs((int)((((vp>>10)&1u)<<5)|(((vp>>9)&1u)<<4)|(vp&15u)), (int)((vp>>4)&31u)) )
  gate<4>(ar,ai,pl2,9); gate<3>(ar,ai,pl2,10); gate<2>(ar,ai,pl2,11);
  gate<1>(ar,ai,pl2,12); gate<0>(ar,ai,pl2,13);
  // T5 (role swap): out regs = [v3 v2 v1 v0 v10], out lanes = [v9 v8 v7 v6 v5 v4]
  XPOSE( const unsigned v=((unsigned)(l>>5)<<10)|((unsigned)((l>>4)&1)<<9)|((unsigned)r<<4)|(unsigned)(l&15); \
         a[r]=lofs((int)((((v>>9)&1u)<<5)|((v>>4)&31u)), (int)(((v&15u)<<1)|((v>>10)&1u))) )
  gate<4>(ar,ai,pl2,14); gate<3>(ar,ai,pl2,15); gate<2>(ar,ai,pl2,16);
  gate<1>(ar,ai,pl2,17);

  // ---- measure: chain2 = C_2(9,8)..(1,0) folded into sign indexing ----
  // lambda_p = s_p ^ s_10 (p<=9), lambda_10 = v10.  Split s = sL(lane) ^ sR(reg):
  // per-lane A_p = hw[17-p]*(-1)^{sL_p}; per-reg signs e_p compile-time.
  float Ghi = 0.f;
#pragma unroll
  for(int jj=0; jj<7; ++jj)
    Ghi += ((hi7>>jj)&1) ? -hw[6-jj] : hw[6-jj];
  const int pA = __popc(l&63)&1, p5 = __popc(l&62)&1, p6 = __popc(l&60)&1;
  const int p7 = __popc(l&56)&1, p8 = __popc(l&48)&1, p9 = (l>>5)&1;
  const float A0 = pA? -hw[17]:hw[17], A1 = pA? -hw[16]:hw[16];
  const float A2 = pA? -hw[15]:hw[15], A3 = pA? -hw[14]:hw[14];
  const float A4 = pA? -hw[13]:hw[13], A5 = p5? -hw[12]:hw[12];
  const float A6 = p6? -hw[11]:hw[11], A7 = p7? -hw[10]:hw[10];
  const float A8 = p8? -hw[9]:hw[9],  A9 = p9? -hw[8]:hw[8];
  const float Hm = Ghi + A4 + A5 + A6 + A7 + A8 + A9;
  const float h7 = hw[7];
  float acc = 0.f;
#pragma unroll
  for(int r=0;r<32;++r){
    const int e3 = (r>>4)&1;
    const int e2 = e3 ^ ((r>>3)&1);
    const int e1 = e2 ^ ((r>>2)&1);
    const int e0 = e1 ^ ((r>>1)&1);
    const int v10 = r&1;
    const float W = Hm + (v10? -h7:h7) + (e3? -A3:A3) + (e2? -A2:A2)
                       + (e1? -A1:A1) + (e0? -A0:A0);
    acc = fmaf(fmaf(ar[r],ar[r], ai[r]*ai[r]), W, acc);
  }
  if (hi7==0 && l==0) acc += hb[0];
#pragma unroll
  for(int off=32; off>0; off>>=1) acc += __shfl_xor(acc, off);
  if (l==0) atomicAdd(&out[b], acc);
}

extern "C" void kernel_launch(void* const* d_in, const int* in_sizes, int n_in,
                              void* d_out, int out_size, void* d_ws, size_t ws_size,
                              hipStream_t stream)
{
  const float* re     = (const float*)d_in[0];
  const float* im     = (const float*)d_in[1];
  unsigned* up        = (unsigned*)d_in[0];   // packed bf16 sigma-layout, in-place
  const float* params = (const float*)d_in[2];
  const float* hw     = (const float*)d_in[3];
  const float* hb     = (const float*)d_in[4];
  float* out          = (float*)d_out;
  (void)in_sizes; (void)n_in; (void)d_ws; (void)ws_size;

  hipMemsetAsync(out, 0, (size_t)out_size * sizeof(float), stream);

  pass1_k<<<dim3(2048), dim3(256), 0, stream>>>(re, im, up, params);
  pass2_k<<<dim3(4096), dim3(128), 0, stream>>>(up, params, hw, hb, out);
}